// Round 1
// baseline (736.725 us; speedup 1.0000x reference)
//
#include <hip/hip_runtime.h>

#define DIMS 1024
#define KNN_K 8

// branchless insert into ascending sorted-8 list (drops the largest)
__device__ __forceinline__ void ins8(float (&lst)[8], float d) {
  float c = d;
  #pragma unroll
  for (int i = 0; i < 8; ++i) {
    float lo = fminf(lst[i], c);
    c = fmaxf(lst[i], c);
    lst[i] = lo;
  }
}

// ---------------- norms: x2[i]=||x_i||^2, y2[j]=||y_j||^2 ----------------
__global__ void norms_kernel(const float* __restrict__ x, const float* __restrict__ y,
                             float* __restrict__ x2, float* __restrict__ y2,
                             int B, int M) {
  int wv = threadIdx.x >> 6;
  int lane = threadIdx.x & 63;
  int row = blockIdx.x * 4 + wv;
  const float* src;
  float* dst;
  if (row < M) {
    src = y + (size_t)row * DIMS; dst = y2 + row;
  } else {
    int r = row - M;
    if (r >= B) return;
    src = x + (size_t)r * DIMS; dst = x2 + r;
  }
  float s = 0.f;
  #pragma unroll
  for (int q = 0; q < DIMS / 4; q += 64) {
    float4 v = ((const float4*)src)[q + lane];
    s = fmaf(v.x, v.x, s); s = fmaf(v.y, v.y, s);
    s = fmaf(v.z, v.z, s); s = fmaf(v.w, v.w, s);
  }
  #pragma unroll
  for (int off = 32; off; off >>= 1) s += __shfl_xor(s, off);
  if (lane == 0) *dst = s;
}

// ---------------- full min_dists -> out copy ----------------
__global__ void copy_kernel(const float4* __restrict__ in, float4* __restrict__ out, int n4) {
  int i = blockIdx.x * blockDim.x + threadIdx.x;
  if (i < n4) out[i] = in[i];
}

// ---------------- phase A: fused GEMM + per-chunk top-8 (squared dists) ----
// grid: (B/32, M/1024). block: 256 threads (4 waves).
// thread (wv = tid>>6 in 0..3, tx = tid&63): rows wv*8+[0,8), cols tx*4+[0,4)
// within each 256-col sub-tile.
#define BM 32
#define BN 256
#define KT 32
#define YS_STRIDE 260   // 256 + 4 pad, keeps 16B alignment, breaks bank cycles

__global__ __launch_bounds__(256, 2) void knn_phaseA(
    const float* __restrict__ x, const float* __restrict__ y,
    const float* __restrict__ x2, const float* __restrict__ y2,
    float* __restrict__ topk_out,          // [B][nchunks*8] squared dists
    const int* __restrict__ xsp, const int* __restrict__ ysp,
    int B, int M, int nchunks) {
  __shared__ float smem[16384];            // 64 KB: compute tiles, then merge
  float* ysm = smem;                       // [KT][YS_STRIDE]
  float* xsm = smem + KT * YS_STRIDE;      // [KT][BM]

  const int tid = threadIdx.x;
  const int wv = tid >> 6;
  const int tx = tid & 63;
  const int r0 = blockIdx.x * BM;
  const int chunk = blockIdx.y;
  const int x_start = *xsp;
  const int y_start = *ysp;
  const float FINF = __builtin_inff();

  float t8[8][8];
  #pragma unroll
  for (int i = 0; i < 8; ++i)
    #pragma unroll
    for (int k = 0; k < 8; ++k) t8[i][k] = FINF;

  float x2v[8];
  #pragma unroll
  for (int i = 0; i < 8; ++i) x2v[i] = x2[r0 + wv * 8 + i];

  for (int cs = 0; cs < 1024 / BN; ++cs) {
    const int c0 = chunk * 1024 + cs * BN;
    float acc[8][4];
    #pragma unroll
    for (int i = 0; i < 8; ++i)
      #pragma unroll
      for (int j = 0; j < 4; ++j) acc[i][j] = 0.f;

    for (int k0 = 0; k0 < DIMS; k0 += KT) {
      __syncthreads();
      // stage y tile: BN x KT floats, transposed into ysm[kk][cc]
      #pragma unroll
      for (int p = 0; p < 8; ++p) {
        int ff = tid + p * 256;
        int cc = ff >> 3;
        int kk4 = ff & 7;
        float4 v = *(const float4*)(y + (size_t)(c0 + cc) * DIMS + k0 + kk4 * 4);
        ysm[(kk4 * 4 + 0) * YS_STRIDE + cc] = v.x;
        ysm[(kk4 * 4 + 1) * YS_STRIDE + cc] = v.y;
        ysm[(kk4 * 4 + 2) * YS_STRIDE + cc] = v.z;
        ysm[(kk4 * 4 + 3) * YS_STRIDE + cc] = v.w;
      }
      // stage x tile: BM x KT floats, transposed into xsm[kk][rr]
      {
        int rr = tid >> 3;
        int kk4 = tid & 7;
        float4 v = *(const float4*)(x + (size_t)(r0 + rr) * DIMS + k0 + kk4 * 4);
        xsm[(kk4 * 4 + 0) * BM + rr] = v.x;
        xsm[(kk4 * 4 + 1) * BM + rr] = v.y;
        xsm[(kk4 * 4 + 2) * BM + rr] = v.z;
        xsm[(kk4 * 4 + 3) * BM + rr] = v.w;
      }
      __syncthreads();
      #pragma unroll
      for (int kk = 0; kk < KT; ++kk) {
        float4 yv = *(const float4*)&ysm[kk * YS_STRIDE + tx * 4];
        float xv[8];
        *(float4*)&xv[0] = *(const float4*)&xsm[kk * BM + wv * 8];
        *(float4*)&xv[4] = *(const float4*)&xsm[kk * BM + wv * 8 + 4];
        #pragma unroll
        for (int i = 0; i < 8; ++i) {
          acc[i][0] = fmaf(xv[i], yv.x, acc[i][0]);
          acc[i][1] = fmaf(xv[i], yv.y, acc[i][1]);
          acc[i][2] = fmaf(xv[i], yv.z, acc[i][2]);
          acc[i][3] = fmaf(xv[i], yv.w, acc[i][3]);
        }
      }
    }
    // epilogue for this sub-tile: squared distance, mask, top-8 insert
    #pragma unroll
    for (int j = 0; j < 4; ++j) {
      int c = c0 + tx * 4 + j;
      float y2v = y2[c];
      #pragma unroll
      for (int i = 0; i < 8; ++i) {
        int r = r0 + wv * 8 + i;
        if (x_start + r == y_start + c) continue;  // self pair -> inf
        float sq = fmaxf(x2v[i] + y2v - 2.f * acc[i][j], 0.f);
        if (sq < t8[i][7]) ins8(t8[i], sq);
      }
    }
  }

  // block-level merge: 64 threads per row-group hold 8 candidates per row
  __syncthreads();
  #pragma unroll
  for (int i = 0; i < 8; ++i)
    #pragma unroll
    for (int k = 0; k < 8; ++k)
      smem[(wv * 8 + i) * 512 + k * 64 + tx] = t8[i][k];  // bank-conflict-free dump
  __syncthreads();
  if (tid < BM) {
    int r = tid;
    float lst[8];
    #pragma unroll
    for (int k = 0; k < 8; ++k) lst[k] = FINF;
    const float* rowp = &smem[r * 512];
    for (int v = 0; v < 512; ++v) {
      float d = rowp[(v + r) & 511];   // rotate start -> distinct banks
      if (d < lst[7]) ins8(lst, d);
    }
    #pragma unroll
    for (int k = 0; k < 8; ++k)
      topk_out[(size_t)(r0 + r) * (nchunks * 8) + chunk * 8 + k] = lst[k];
  }
}

// ---------------- phase B: merge chunk candidates + running min_dists ------
__global__ void knn_phaseB(const float* __restrict__ topk,
                           const float* __restrict__ mind_in,
                           float* __restrict__ out,
                           const int* __restrict__ xsp, int B, int nchunks) {
  int r = blockIdx.x * blockDim.x + threadIdx.x;
  if (r >= B) return;
  int x_start = *xsp;
  const float FINF = __builtin_inff();
  float lst[8];
  #pragma unroll
  for (int k = 0; k < 8; ++k) lst[k] = FINF;
  const int nc = nchunks * 8;
  const float* rowp = topk + (size_t)r * nc;
  for (int v = 0; v < nc; ++v) {
    float d = sqrtf(rowp[v]);          // squared -> distance (inf stays inf)
    if (d < lst[7]) ins8(lst, d);
  }
  const float* cur = mind_in + (size_t)(x_start + r) * KNN_K;
  #pragma unroll
  for (int k = 0; k < 8; ++k) {
    float d = cur[k];
    if (d < lst[7]) ins8(lst, d);
  }
  #pragma unroll
  for (int k = 0; k < 8; ++k) out[(size_t)(x_start + r) * KNN_K + k] = lst[k];
}

extern "C" void kernel_launch(void* const* d_in, const int* in_sizes, int n_in,
                              void* d_out, int out_size, void* d_ws, size_t ws_size,
                              hipStream_t stream) {
  const float* x = (const float*)d_in[0];
  const float* y = (const float*)d_in[1];
  const float* mind = (const float*)d_in[2];
  const int* xsp = (const int*)d_in[3];
  const int* ysp = (const int*)d_in[4];
  float* out = (float*)d_out;

  const int B = in_sizes[0] / DIMS;       // 2048
  const int M = in_sizes[1] / DIMS;       // 8192
  const int nchunks = M / 1024;           // 8

  float* y2 = (float*)d_ws;               // [M]
  float* x2 = y2 + M;                     // [B]
  float* topk = x2 + B;                   // [B][nchunks*8]

  int nrows = B + M;
  norms_kernel<<<(nrows + 3) / 4, 256, 0, stream>>>(x, y, x2, y2, B, M);

  int n4 = out_size / 4;
  copy_kernel<<<(n4 + 255) / 256, 256, 0, stream>>>((const float4*)mind, (float4*)out, n4);

  dim3 ga(B / BM, nchunks);
  knn_phaseA<<<ga, 256, 0, stream>>>(x, y, x2, y2, topk, xsp, ysp, B, M, nchunks);

  knn_phaseB<<<(B + 255) / 256, 256, 0, stream>>>(topk, mind, out, xsp, B, nchunks);
}

// Round 2
// 183.382 us; speedup vs baseline: 4.0174x; 4.0174x over previous
//
#include <hip/hip_runtime.h>

#define DIMS 1024
#define KNN_K 8
#define BM 128
#define BN 128
#define CS 2            // column sub-tiles per block -> 256 cols/block
#define KT 64           // K-step (bf16 row = 128B in LDS)

typedef __bf16 bf16;
typedef __bf16 bf16x8 __attribute__((ext_vector_type(8)));
typedef __bf16 bf16x4 __attribute__((ext_vector_type(4)));
typedef float f32x4 __attribute__((ext_vector_type(4)));

// branchless insert into ascending sorted-8 list (drops the largest)
__device__ __forceinline__ void ins8(float (&lst)[8], float d) {
  float c = d;
  #pragma unroll
  for (int i = 0; i < 8; ++i) {
    float lo = fminf(lst[i], c);
    c = fmaxf(lst[i], c);
    lst[i] = lo;
  }
}

__device__ __forceinline__ void gload_lds16(const void* g, void* l) {
  __builtin_amdgcn_global_load_lds(
      (const __attribute__((address_space(1))) void*)g,
      (__attribute__((address_space(3))) void*)l, 16, 0, 0);
}

// ---------------- norms (+ optional bf16 convert): one wave per row --------
template<bool PRE>
__global__ void norms_kernel(const float* __restrict__ x, const float* __restrict__ y,
                             float* __restrict__ x2, float* __restrict__ y2,
                             bf16* __restrict__ xb, bf16* __restrict__ yb,
                             int B, int M) {
  int wv = threadIdx.x >> 6;
  int lane = threadIdx.x & 63;
  int row = blockIdx.x * 4 + wv;
  const float* src;
  float* dst;
  bf16* bdst;
  if (row < M) {
    src = y + (size_t)row * DIMS; dst = y2 + row; bdst = yb + (size_t)row * DIMS;
  } else {
    int r = row - M;
    if (r >= B) return;
    src = x + (size_t)r * DIMS; dst = x2 + r; bdst = xb + (size_t)r * DIMS;
  }
  float s = 0.f;
  #pragma unroll
  for (int q = 0; q < DIMS / 4; q += 64) {
    float4 v = ((const float4*)src)[q + lane];
    s = fmaf(v.x, v.x, s); s = fmaf(v.y, v.y, s);
    s = fmaf(v.z, v.z, s); s = fmaf(v.w, v.w, s);
    if (PRE) {
      bf16x4 bv = {(bf16)v.x, (bf16)v.y, (bf16)v.z, (bf16)v.w};
      *(bf16x4*)(bdst + (size_t)(q + lane) * 4) = bv;
    }
  }
  #pragma unroll
  for (int off = 32; off; off >>= 1) s += __shfl_xor(s, off);
  if (lane == 0) *dst = s;
}

// ---------------- full min_dists -> out copy ----------------
__global__ void copy_kernel(const float4* __restrict__ in, float4* __restrict__ out, int n4) {
  int i = blockIdx.x * blockDim.x + threadIdx.x;
  if (i < n4) out[i] = in[i];
}

// ---------------- phase A: bf16 MFMA GEMM + fused per-chunk top-8 ----------
// grid (B/BM, M/(BN*CS)); block 256 threads = 4 waves (2x2 wave grid).
// Wave (wr,wc) computes 64x64 via 4x4 fragments of 16x16x32 bf16 MFMA.
template<bool PRE>
__global__ __launch_bounds__(256, 3) void knn_mfma(
    const float* __restrict__ xf, const float* __restrict__ yf,
    const bf16* __restrict__ xb, const bf16* __restrict__ yb,
    const float* __restrict__ x2, const float* __restrict__ y2,
    float* __restrict__ topk_out,           // [B][nchunks*8] squared dists
    const int* __restrict__ xsp, const int* __restrict__ ysp,
    int B, int M, int nchunks) {
  __shared__ __align__(16) char smem[32768];
  bf16* xls = (bf16*)smem;                  // [128][64] bf16, XOR-swizzled 16B slots
  bf16* yls = (bf16*)(smem + 16384);        // [128][64]
  float* eps = (float*)smem;                // epilogue reuse: [64][128] f32
  __shared__ float x2s[BM];
  __shared__ float y2s[BN * CS];

  const int tid = threadIdx.x;
  const int wv = tid >> 6;
  const int l = tid & 63;
  const int wr = wv >> 1, wc = wv & 1;
  const int g4 = l >> 4;
  const int l16 = l & 15;
  const int r0 = blockIdx.x * BM;
  const int cc0 = blockIdx.y * (BN * CS);
  const int xs = *xsp, ys = *ysp;
  const float FINF = __builtin_inff();

  if (tid < BM) x2s[tid] = x2[r0 + tid];
  y2s[tid] = y2[cc0 + tid];                 // 256 threads cover BN*CS

  float t8[8];
  #pragma unroll
  for (int k = 0; k < 8; ++k) t8[k] = FINF;

  for (int cs = 0; cs < CS; ++cs) {
    const int c0 = cc0 + cs * BN;
    f32x4 acc[4][4];
    #pragma unroll
    for (int mi = 0; mi < 4; ++mi)
      #pragma unroll
      for (int ni = 0; ni < 4; ++ni)
        acc[mi][ni] = (f32x4){0.f, 0.f, 0.f, 0.f};

    for (int k0 = 0; k0 < DIMS; k0 += KT) {
      __syncthreads();                       // LDS free (prev compute/epilogue done)
      if (PRE) {
        #pragma unroll
        for (int p = 0; p < 4; ++p) {
          int rr = p * 32 + (tid >> 3);
          int ks = (tid & 7) ^ (rr & 7);     // pre-swizzled global source
          gload_lds16(xb + (size_t)(r0 + rr) * DIMS + k0 + ks * 8,
                      (char*)xls + p * 4096 + tid * 16);
          gload_lds16(yb + (size_t)(c0 + rr) * DIMS + k0 + ks * 8,
                      (char*)yls + p * 4096 + tid * 16);
        }
      } else {
        #pragma unroll
        for (int p = 0; p < 4; ++p) {
          int rr = p * 32 + (tid >> 3);
          int sl = tid & 7;
          const float* gx = xf + (size_t)(r0 + rr) * DIMS + k0 + sl * 8;
          float4 a0 = *(const float4*)gx;
          float4 a1 = *(const float4*)(gx + 4);
          bf16x8 bx = {(bf16)a0.x, (bf16)a0.y, (bf16)a0.z, (bf16)a0.w,
                       (bf16)a1.x, (bf16)a1.y, (bf16)a1.z, (bf16)a1.w};
          *(bf16x8*)((char*)xls + rr * 128 + ((sl ^ (rr & 7)) * 16)) = bx;
          const float* gy = yf + (size_t)(c0 + rr) * DIMS + k0 + sl * 8;
          float4 b0 = *(const float4*)gy;
          float4 b1 = *(const float4*)(gy + 4);
          bf16x8 by = {(bf16)b0.x, (bf16)b0.y, (bf16)b0.z, (bf16)b0.w,
                       (bf16)b1.x, (bf16)b1.y, (bf16)b1.z, (bf16)b1.w};
          *(bf16x8*)((char*)yls + rr * 128 + ((sl ^ (rr & 7)) * 16)) = by;
        }
      }
      __syncthreads();
      #pragma unroll
      for (int kk = 0; kk < 2; ++kk) {
        bf16x8 af[4], bfr[4];
        #pragma unroll
        for (int mi = 0; mi < 4; ++mi) {
          int row = wr * 64 + mi * 16 + l16;
          int slot = (kk * 4 + g4) ^ (row & 7);
          af[mi] = *(const bf16x8*)((char*)xls + row * 128 + slot * 16);
        }
        #pragma unroll
        for (int ni = 0; ni < 4; ++ni) {
          int col = wc * 64 + ni * 16 + l16;
          int slot = (kk * 4 + g4) ^ (col & 7);
          bfr[ni] = *(const bf16x8*)((char*)yls + col * 128 + slot * 16);
        }
        #pragma unroll
        for (int mi = 0; mi < 4; ++mi)
          #pragma unroll
          for (int ni = 0; ni < 4; ++ni)
            acc[mi][ni] = __builtin_amdgcn_mfma_f32_16x16x32_bf16(
                af[mi], bfr[ni], acc[mi][ni], 0, 0, 0);
      }
    }

    // epilogue: two row-half phases through the reused 32KB LDS
    #pragma unroll
    for (int h = 0; h < 2; ++h) {
      __syncthreads();
      if (wr == h) {
        #pragma unroll
        for (int mi = 0; mi < 4; ++mi)
          #pragma unroll
          for (int reg = 0; reg < 4; ++reg) {
            int rh = mi * 16 + g4 * 4 + reg;        // row within half
            int r = r0 + h * 64 + rh;               // global x row
            float xv = x2s[h * 64 + rh];
            #pragma unroll
            for (int ni = 0; ni < 4; ++ni) {
              int cb = wc * 64 + ni * 16 + l16;
              int c = c0 + cb;                      // global y row
              float sq = fmaxf(xv + y2s[cs * BN + cb] - 2.f * acc[mi][ni][reg], 0.f);
              if (xs + r == ys + c) sq = FINF;      // self pair
              int cw = cb ^ (((rh >> 2) & 1) << 4); // bank spread
              eps[rh * 128 + cw] = sq;
            }
          }
      }
      __syncthreads();
      if (tid >= h * 64 && tid < h * 64 + 64) {     // thread tid owns row r0+tid
        int rh = tid & 63;
        int sw = ((rh >> 2) & 1) << 2;
        for (int i = 0; i < 32; ++i) {
          int j = ((i + rh) & 31) ^ sw;             // rotate + inverse swizzle
          f32x4 v = *(const f32x4*)&eps[rh * 128 + j * 4];
          if (v[0] < t8[7]) ins8(t8, v[0]);
          if (v[1] < t8[7]) ins8(t8, v[1]);
          if (v[2] < t8[7]) ins8(t8, v[2]);
          if (v[3] < t8[7]) ins8(t8, v[3]);
        }
      }
    }
  }

  if (tid < BM) {
    float* o = topk_out + (size_t)(r0 + tid) * (nchunks * 8) + blockIdx.y * 8;
    #pragma unroll
    for (int k = 0; k < 8; ++k) o[k] = t8[k];
  }
}

// ---------------- phase B: merge chunk candidates + running min_dists ------
__global__ void knn_phaseB(const float* __restrict__ topk,
                           const float* __restrict__ mind_in,
                           float* __restrict__ out,
                           const int* __restrict__ xsp, int B, int nchunks) {
  int r = blockIdx.x * blockDim.x + threadIdx.x;
  if (r >= B) return;
  int x_start = *xsp;
  const float FINF = __builtin_inff();
  float lst[8];
  #pragma unroll
  for (int k = 0; k < 8; ++k) lst[k] = FINF;
  const int nc = nchunks * 8;
  const float* rowp = topk + (size_t)r * nc;
  for (int v = 0; v < nc; ++v) {
    float d = sqrtf(rowp[v]);
    if (d < lst[7]) ins8(lst, d);
  }
  const float* cur = mind_in + (size_t)(x_start + r) * KNN_K;
  #pragma unroll
  for (int k = 0; k < 8; ++k) {
    float d = cur[k];
    if (d < lst[7]) ins8(lst, d);
  }
  #pragma unroll
  for (int k = 0; k < 8; ++k) out[(size_t)(x_start + r) * KNN_K + k] = lst[k];
}

extern "C" void kernel_launch(void* const* d_in, const int* in_sizes, int n_in,
                              void* d_out, int out_size, void* d_ws, size_t ws_size,
                              hipStream_t stream) {
  const float* x = (const float*)d_in[0];
  const float* y = (const float*)d_in[1];
  const float* mind = (const float*)d_in[2];
  const int* xsp = (const int*)d_in[3];
  const int* ysp = (const int*)d_in[4];
  float* out = (float*)d_out;

  const int B = in_sizes[0] / DIMS;       // 2048
  const int M = in_sizes[1] / DIMS;       // 8192
  const int nch = M / (BN * CS);          // 32

  float* y2 = (float*)d_ws;               // [M]
  float* x2 = y2 + M;                     // [B]
  float* topk = x2 + B;                   // [B][nch*8]
  size_t base = ((size_t)(M + B) + (size_t)B * nch * 8) * 4;
  base = (base + 255) & ~(size_t)255;
  bf16* xbw = (bf16*)((char*)d_ws + base);
  bf16* ybw = xbw + (size_t)B * DIMS;
  size_t need = base + ((size_t)B + (size_t)M) * DIMS * 2;
  bool pre = ws_size >= need;

  int nrows = B + M;
  if (pre)
    norms_kernel<true><<<(nrows + 3) / 4, 256, 0, stream>>>(x, y, x2, y2, xbw, ybw, B, M);
  else
    norms_kernel<false><<<(nrows + 3) / 4, 256, 0, stream>>>(x, y, x2, y2, xbw, ybw, B, M);

  int n4 = out_size / 4;
  copy_kernel<<<(n4 + 255) / 256, 256, 0, stream>>>((const float4*)mind, (float4*)out, n4);

  dim3 ga(B / BM, nch);
  if (pre)
    knn_mfma<true><<<ga, 256, 0, stream>>>(x, y, xbw, ybw, x2, y2, topk, xsp, ysp, B, M, nch);
  else
    knn_mfma<false><<<ga, 256, 0, stream>>>(x, y, xbw, ybw, x2, y2, topk, xsp, ysp, B, M, nch);

  knn_phaseB<<<(B + 255) / 256, 256, 0, stream>>>(topk, mind, out, xsp, B, nch);
}

// Round 3
// 154.909 us; speedup vs baseline: 4.7558x; 1.1838x over previous
//
#include <hip/hip_runtime.h>

#define DIMS 1024
#define KNN_K 8
#define BM 128
#define BN 128
#define CS 2            // column sub-tiles per block -> 256 cols/block
#define KT 64           // K-step (bf16 row = 128B in LDS)

typedef __bf16 bf16;
typedef __bf16 bf16x8 __attribute__((ext_vector_type(8)));
typedef __bf16 bf16x4 __attribute__((ext_vector_type(4)));
typedef float f32x4 __attribute__((ext_vector_type(4)));

// branchless insert into ascending sorted-8 list (drops the largest)
__device__ __forceinline__ void ins8(float (&lst)[8], float d) {
  float c = d;
  #pragma unroll
  for (int i = 0; i < 8; ++i) {
    float lo = fminf(lst[i], c);
    c = fmaxf(lst[i], c);
    lst[i] = lo;
  }
}

__device__ __forceinline__ void gload_lds16(const void* g, void* l) {
  __builtin_amdgcn_global_load_lds(
      (const __attribute__((address_space(1))) void*)g,
      (__attribute__((address_space(3))) void*)l, 16, 0, 0);
}

// ---- prep: norms (+ optional bf16 convert) fused with min_dists->out copy --
template<bool PRE>
__global__ void prep_kernel(const float* __restrict__ x, const float* __restrict__ y,
                            float* __restrict__ x2, float* __restrict__ y2,
                            bf16* __restrict__ xb, bf16* __restrict__ yb,
                            const float4* __restrict__ mind4, float4* __restrict__ out4,
                            int n4, int B, int M, int nNormBlocks) {
  if ((int)blockIdx.x >= nNormBlocks) {        // tail blocks: full-buffer copy
    int i = ((int)blockIdx.x - nNormBlocks) * 256 + threadIdx.x;
    if (i < n4) out4[i] = mind4[i];
    return;
  }
  int wv = threadIdx.x >> 6;
  int lane = threadIdx.x & 63;
  int row = blockIdx.x * 4 + wv;
  const float* src;
  float* dst;
  bf16* bdst;
  if (row < M) {
    src = y + (size_t)row * DIMS; dst = y2 + row; bdst = yb + (size_t)row * DIMS;
  } else {
    int r = row - M;
    if (r >= B) return;
    src = x + (size_t)r * DIMS; dst = x2 + r; bdst = xb + (size_t)r * DIMS;
  }
  float s = 0.f;
  #pragma unroll
  for (int q = 0; q < DIMS / 4; q += 64) {
    float4 v = ((const float4*)src)[q + lane];
    s = fmaf(v.x, v.x, s); s = fmaf(v.y, v.y, s);
    s = fmaf(v.z, v.z, s); s = fmaf(v.w, v.w, s);
    if (PRE) {
      bf16x4 bv = {(bf16)v.x, (bf16)v.y, (bf16)v.z, (bf16)v.w};
      *(bf16x4*)(bdst + (size_t)(q + lane) * 4) = bv;
    }
  }
  #pragma unroll
  for (int off = 32; off; off >>= 1) s += __shfl_xor(s, off);
  if (lane == 0) *dst = s;
}

// ---------------- phase A: bf16 MFMA GEMM + fused per-chunk top-8 ----------
// grid (B/BM, M/(BN*CS)); block 256 threads = 4 waves (2x2 wave grid).
// Double-buffered LDS staging, counted vmcnt, raw barriers (T3-minimum).
template<bool PRE>
__global__ __launch_bounds__(256, 2) void knn_mfma(
    const float* __restrict__ xf, const float* __restrict__ yf,
    const bf16* __restrict__ xb, const bf16* __restrict__ yb,
    const float* __restrict__ x2, const float* __restrict__ y2,
    float* __restrict__ topk_out,           // [B][nchunks*8] squared dists
    const int* __restrict__ xsp, const int* __restrict__ ysp,
    int B, int M, int nchunks) {
  __shared__ __align__(16) char smem[65536];  // 2 buffers x (x 16KB + y 16KB)
  __shared__ float x2s[BM];
  __shared__ float y2s[BN * CS];
  float* eps = (float*)smem;                  // epilogue reuse: buf0, [64][128] f32

  const int tid = threadIdx.x;
  const int wv = tid >> 6;
  const int l = tid & 63;
  const int wr = wv >> 1, wc = wv & 1;
  const int g4 = l >> 4;
  const int l16 = l & 15;
  const int r0 = blockIdx.x * BM;
  const int cc0 = blockIdx.y * (BN * CS);
  const int xs = *xsp, ys = *ysp;
  const float FINF = __builtin_inff();

  if (tid < BM) x2s[tid] = x2[r0 + tid];
  y2s[tid] = y2[cc0 + tid];

  float t8[8];
  #pragma unroll
  for (int k = 0; k < 8; ++k) t8[k] = FINF;

  f32x4 acc[4][4];

  auto STAGE = [&](int b, int c0, int k0) {
    char* xd = smem + b * 32768;
    char* yd = xd + 16384;
    if (PRE) {
      #pragma unroll
      for (int p = 0; p < 4; ++p) {
        int rr = p * 32 + (tid >> 3);
        int ks = (tid & 7) ^ (rr & 7);       // pre-swizzled global source
        gload_lds16(xb + (size_t)(r0 + rr) * DIMS + k0 + ks * 8,
                    xd + p * 4096 + tid * 16);
        gload_lds16(yb + (size_t)(c0 + rr) * DIMS + k0 + ks * 8,
                    yd + p * 4096 + tid * 16);
      }
    } else {
      #pragma unroll
      for (int p = 0; p < 4; ++p) {
        int rr = p * 32 + (tid >> 3);
        int sl = tid & 7;
        const float* gx = xf + (size_t)(r0 + rr) * DIMS + k0 + sl * 8;
        float4 a0 = *(const float4*)gx;
        float4 a1 = *(const float4*)(gx + 4);
        bf16x8 bx = {(bf16)a0.x, (bf16)a0.y, (bf16)a0.z, (bf16)a0.w,
                     (bf16)a1.x, (bf16)a1.y, (bf16)a1.z, (bf16)a1.w};
        *(bf16x8*)(xd + rr * 128 + ((sl ^ (rr & 7)) * 16)) = bx;
        const float* gy = yf + (size_t)(c0 + rr) * DIMS + k0 + sl * 8;
        float4 b0 = *(const float4*)gy;
        float4 b1 = *(const float4*)(gy + 4);
        bf16x8 by = {(bf16)b0.x, (bf16)b0.y, (bf16)b0.z, (bf16)b0.w,
                     (bf16)b1.x, (bf16)b1.y, (bf16)b1.z, (bf16)b1.w};
        *(bf16x8*)(yd + rr * 128 + ((sl ^ (rr & 7)) * 16)) = by;
      }
    }
  };

  auto COMPUTE = [&](int b) {
    const char* xd = smem + b * 32768;
    const char* yd = xd + 16384;
    #pragma unroll
    for (int kk = 0; kk < 2; ++kk) {
      bf16x8 af[4], bfr[4];
      #pragma unroll
      for (int mi = 0; mi < 4; ++mi) {
        int row = wr * 64 + mi * 16 + l16;
        int slot = (kk * 4 + g4) ^ (row & 7);
        af[mi] = *(const bf16x8*)(xd + row * 128 + slot * 16);
      }
      #pragma unroll
      for (int ni = 0; ni < 4; ++ni) {
        int col = wc * 64 + ni * 16 + l16;
        int slot = (kk * 4 + g4) ^ (col & 7);
        bfr[ni] = *(const bf16x8*)(yd + col * 128 + slot * 16);
      }
      #pragma unroll
      for (int mi = 0; mi < 4; ++mi)
        #pragma unroll
        for (int ni = 0; ni < 4; ++ni)
          acc[mi][ni] = __builtin_amdgcn_mfma_f32_16x16x32_bf16(
              af[mi], bfr[ni], acc[mi][ni], 0, 0, 0);
    }
  };

  int cur = 1;
  STAGE(1, cc0, 0);                            // prologue: cs0 tile0 -> buf1
  for (int cs = 0; cs < CS; ++cs) {
    const int c0 = cc0 + cs * BN;
    #pragma unroll
    for (int mi = 0; mi < 4; ++mi)
      #pragma unroll
      for (int ni = 0; ni < 4; ++ni)
        acc[mi][ni] = (f32x4){0.f, 0.f, 0.f, 0.f};

    for (int k0 = 0; k0 < DIMS; k0 += KT) {
      bool more = (k0 + KT < DIMS) || (cs + 1 < CS);
      if (k0 + KT < DIMS)      STAGE(cur ^ 1, c0, k0 + KT);
      else if (cs + 1 < CS)    STAGE(cur ^ 1, c0 + BN, 0);   // cross-cs prefetch
      if (PRE) {
        if (more) asm volatile("s_waitcnt vmcnt(8)" ::: "memory");
        else      asm volatile("s_waitcnt vmcnt(0)" ::: "memory");
        __builtin_amdgcn_s_barrier();
        __builtin_amdgcn_sched_barrier(0);     // rule 18: no ds_read hoisting
      } else {
        __syncthreads();
      }
      COMPUTE(cur);
      if (PRE) __builtin_amdgcn_s_barrier();   // all waves done reading buf[cur]
      else     __syncthreads();
      cur ^= 1;
    }

    // epilogue: two row-half phases through eps (= buf0; last tile was buf0,
    // cross-cs prefetch targets buf1 -> no overlap with in-flight DMA)
    #pragma unroll
    for (int h = 0; h < 2; ++h) {
      __syncthreads();
      if (wr == h) {
        #pragma unroll
        for (int mi = 0; mi < 4; ++mi)
          #pragma unroll
          for (int reg = 0; reg < 4; ++reg) {
            int rh = mi * 16 + g4 * 4 + reg;        // row within half
            int r = r0 + h * 64 + rh;               // global x row
            float xv = x2s[h * 64 + rh];
            #pragma unroll
            for (int ni = 0; ni < 4; ++ni) {
              int cb = wc * 64 + ni * 16 + l16;
              int c = c0 + cb;                      // global y row
              float sq = fmaxf(xv + y2s[cs * BN + cb] - 2.f * acc[mi][ni][reg], 0.f);
              if (xs + r == ys + c) sq = FINF;      // self pair
              int cw = cb ^ (((rh >> 2) & 1) << 4); // bank spread
              eps[rh * 128 + cw] = sq;
            }
          }
      }
      __syncthreads();
      if (tid >= h * 64 && tid < h * 64 + 64) {     // thread tid owns row r0+tid
        int rh = tid & 63;
        int sw = ((rh >> 2) & 1) << 2;
        for (int i = 0; i < 32; ++i) {
          int j = ((i + rh) & 31) ^ sw;             // rotate + inverse swizzle
          f32x4 v = *(const f32x4*)&eps[rh * 128 + j * 4];
          if (v[0] < t8[7]) ins8(t8, v[0]);
          if (v[1] < t8[7]) ins8(t8, v[1]);
          if (v[2] < t8[7]) ins8(t8, v[2]);
          if (v[3] < t8[7]) ins8(t8, v[3]);
        }
      }
    }
    __syncthreads();   // protect eps (buf0) before next cs stages into buf0
  }

  if (tid < BM) {
    float* o = topk_out + (size_t)(r0 + tid) * (nchunks * 8) + blockIdx.y * 8;
    #pragma unroll
    for (int k = 0; k < 8; ++k) o[k] = t8[k];
  }
}

// ---------------- phase B: merge chunk candidates + running min_dists ------
__global__ void knn_phaseB(const float* __restrict__ topk,
                           const float* __restrict__ mind_in,
                           float* __restrict__ out,
                           const int* __restrict__ xsp, int B, int nchunks) {
  int r = blockIdx.x * blockDim.x + threadIdx.x;
  if (r >= B) return;
  int x_start = *xsp;
  const float FINF = __builtin_inff();
  float lst[8];
  #pragma unroll
  for (int k = 0; k < 8; ++k) lst[k] = FINF;
  const int nc = nchunks * 8;
  const float* rowp = topk + (size_t)r * nc;
  for (int v = 0; v < nc; ++v) {
    float d = sqrtf(rowp[v]);
    if (d < lst[7]) ins8(lst, d);
  }
  const float* cur = mind_in + (size_t)(x_start + r) * KNN_K;
  #pragma unroll
  for (int k = 0; k < 8; ++k) {
    float d = cur[k];
    if (d < lst[7]) ins8(lst, d);
  }
  #pragma unroll
  for (int k = 0; k < 8; ++k) out[(size_t)(x_start + r) * KNN_K + k] = lst[k];
}

extern "C" void kernel_launch(void* const* d_in, const int* in_sizes, int n_in,
                              void* d_out, int out_size, void* d_ws, size_t ws_size,
                              hipStream_t stream) {
  const float* x = (const float*)d_in[0];
  const float* y = (const float*)d_in[1];
  const float* mind = (const float*)d_in[2];
  const int* xsp = (const int*)d_in[3];
  const int* ysp = (const int*)d_in[4];
  float* out = (float*)d_out;

  const int B = in_sizes[0] / DIMS;       // 2048
  const int M = in_sizes[1] / DIMS;       // 8192
  const int nch = M / (BN * CS);          // 32

  float* y2 = (float*)d_ws;               // [M]
  float* x2 = y2 + M;                     // [B]
  float* topk = x2 + B;                   // [B][nch*8]
  size_t base = ((size_t)(M + B) + (size_t)B * nch * 8) * 4;
  base = (base + 255) & ~(size_t)255;
  bf16* xbw = (bf16*)((char*)d_ws + base);
  bf16* ybw = xbw + (size_t)B * DIMS;
  size_t need = base + ((size_t)B + (size_t)M) * DIMS * 2;
  bool pre = ws_size >= need;

  int nNorm = (B + M + 3) / 4;
  int n4 = out_size / 4;
  int nCopy = (n4 + 255) / 256;
  if (pre)
    prep_kernel<true><<<nNorm + nCopy, 256, 0, stream>>>(
        x, y, x2, y2, xbw, ybw, (const float4*)mind, (float4*)out, n4, B, M, nNorm);
  else
    prep_kernel<false><<<nNorm + nCopy, 256, 0, stream>>>(
        x, y, x2, y2, xbw, ybw, (const float4*)mind, (float4*)out, n4, B, M, nNorm);

  dim3 ga(B / BM, nch);
  if (pre)
    knn_mfma<true><<<ga, 256, 0, stream>>>(x, y, xbw, ybw, x2, y2, topk, xsp, ysp, B, M, nch);
  else
    knn_mfma<false><<<ga, 256, 0, stream>>>(x, y, xbw, ybw, x2, y2, topk, xsp, ysp, B, M, nch);

  knn_phaseB<<<(B + 255) / 256, 256, 0, stream>>>(topk, mind, out, xsp, B, nch);
}

// Round 4
// 154.569 us; speedup vs baseline: 4.7663x; 1.0022x over previous
//
#include <hip/hip_runtime.h>

#define DIMS 1024
#define KNN_K 8
#define BM 256
#define BN 256
#define KT 64
#define EPS_LD 264

typedef __bf16 bf16;
typedef __bf16 bf16x8 __attribute__((ext_vector_type(8)));
typedef __bf16 bf16x4 __attribute__((ext_vector_type(4)));
typedef float f32x4 __attribute__((ext_vector_type(4)));

// branchless insert into ascending sorted-8 list (drops the largest)
__device__ __forceinline__ void ins8(float (&lst)[8], float d) {
  float c = d;
  #pragma unroll
  for (int i = 0; i < 8; ++i) {
    float lo = fminf(lst[i], c);
    c = fmaxf(lst[i], c);
    lst[i] = lo;
  }
}

__device__ __forceinline__ void gload_lds16(const void* g, void* l) {
  __builtin_amdgcn_global_load_lds(
      (const __attribute__((address_space(1))) void*)g,
      (__attribute__((address_space(3))) void*)l, 16, 0, 0);
}

// ---- prep: norms (+ optional bf16 convert) fused with min_dists->out copy --
template<bool PRE>
__global__ void prep_kernel(const float* __restrict__ x, const float* __restrict__ y,
                            float* __restrict__ x2, float* __restrict__ y2,
                            bf16* __restrict__ xb, bf16* __restrict__ yb,
                            const float4* __restrict__ mind4, float4* __restrict__ out4,
                            int n4, int B, int M, int nNormBlocks) {
  if ((int)blockIdx.x >= nNormBlocks) {        // tail blocks: full-buffer copy
    int i = ((int)blockIdx.x - nNormBlocks) * 256 + threadIdx.x;
    if (i < n4) out4[i] = mind4[i];
    return;
  }
  int wv = threadIdx.x >> 6;
  int lane = threadIdx.x & 63;
  int row = blockIdx.x * 4 + wv;
  const float* src;
  float* dst;
  bf16* bdst;
  if (row < M) {
    src = y + (size_t)row * DIMS; dst = y2 + row; bdst = yb + (size_t)row * DIMS;
  } else {
    int r = row - M;
    if (r >= B) return;
    src = x + (size_t)r * DIMS; dst = x2 + r; bdst = xb + (size_t)r * DIMS;
  }
  float s = 0.f;
  #pragma unroll
  for (int q = 0; q < DIMS / 4; q += 64) {
    float4 v = ((const float4*)src)[q + lane];
    s = fmaf(v.x, v.x, s); s = fmaf(v.y, v.y, s);
    s = fmaf(v.z, v.z, s); s = fmaf(v.w, v.w, s);
    if (PRE) {
      bf16x4 bv = {(bf16)v.x, (bf16)v.y, (bf16)v.z, (bf16)v.w};
      *(bf16x4*)(bdst + (size_t)(q + lane) * 4) = bv;
    }
  }
  #pragma unroll
  for (int off = 32; off; off >>= 1) s += __shfl_xor(s, off);
  if (lane == 0) *dst = s;
}

// ---------------- phase A: 256x256 bf16 MFMA GEMM + fused top-8 ------------
// grid (B/256, M/256); block 512 threads = 8 waves (2M x 4N). Per wave 128x64.
// One barrier + one vmem drain per K-tile; stages issued 3 phases ahead.
template<bool PRE>
__global__ __launch_bounds__(512, 2) void knn_mfma(
    const float* __restrict__ xf, const float* __restrict__ yf,
    const bf16* __restrict__ xb, const bf16* __restrict__ yb,
    const float* __restrict__ x2, const float* __restrict__ y2,
    float* __restrict__ topk_out,           // [B][nchunks*8] squared dists
    const int* __restrict__ xsp, const int* __restrict__ ysp,
    int B, int M, int nchunks) {
  __shared__ __align__(16) char smem[131072]; // 2 x (A 32KB + B 32KB)
  float* eps = (float*)smem;                  // epilogue reuse [64][EPS_LD]
  float* part = (float*)(smem + 114688);      // [64][16] partial top-8s

  const int tid = threadIdx.x;
  const int wv = tid >> 6;
  const int l = tid & 63;
  const int wr = wv >> 2, wc = wv & 3;
  const int g4 = l >> 4, l16 = l & 15;
  const int r0 = blockIdx.x * BM;
  const int c0 = blockIdx.y * BN;
  const int xs = *xsp, ys = *ysp;
  const float FINF = __builtin_inff();

  f32x4 acc[8][4];
  #pragma unroll
  for (int mi = 0; mi < 8; ++mi)
    #pragma unroll
    for (int ni = 0; ni < 4; ++ni)
      acc[mi][ni] = (f32x4){0.f, 0.f, 0.f, 0.f};

  auto STAGE = [&](int b, int k0) {
    char* xd = smem + b * 65536;
    char* yd = xd + 32768;
    if (PRE) {
      #pragma unroll
      for (int p = 0; p < 4; ++p) {
        int rr = p * 64 + (tid >> 3);
        int ks = (tid & 7) ^ (rr & 7);       // pre-swizzled global source
        gload_lds16(xb + (size_t)(r0 + rr) * DIMS + k0 + ks * 8,
                    xd + p * 8192 + tid * 16);
      }
      #pragma unroll
      for (int p = 0; p < 4; ++p) {
        int rr = p * 64 + (tid >> 3);
        int ks = (tid & 7) ^ (rr & 7);
        gload_lds16(yb + (size_t)(c0 + rr) * DIMS + k0 + ks * 8,
                    yd + p * 8192 + tid * 16);
      }
    } else {
      #pragma unroll
      for (int p = 0; p < 4; ++p) {
        int rr = p * 64 + (tid >> 3);
        int sl = tid & 7;
        const float* gx = xf + (size_t)(r0 + rr) * DIMS + k0 + sl * 8;
        float4 a0 = *(const float4*)gx;
        float4 a1 = *(const float4*)(gx + 4);
        bf16x8 bx = {(bf16)a0.x, (bf16)a0.y, (bf16)a0.z, (bf16)a0.w,
                     (bf16)a1.x, (bf16)a1.y, (bf16)a1.z, (bf16)a1.w};
        *(bf16x8*)(xd + rr * 128 + ((sl ^ (rr & 7)) * 16)) = bx;
        const float* gy = yf + (size_t)(c0 + rr) * DIMS + k0 + sl * 8;
        float4 b0 = *(const float4*)gy;
        float4 b1 = *(const float4*)(gy + 4);
        bf16x8 by = {(bf16)b0.x, (bf16)b0.y, (bf16)b0.z, (bf16)b0.w,
                     (bf16)b1.x, (bf16)b1.y, (bf16)b1.z, (bf16)b1.w};
        *(bf16x8*)(yd + rr * 128 + ((sl ^ (rr & 7)) * 16)) = by;
      }
    }
  };

  if (PRE) STAGE(0, 0);                      // prologue: tile 0 in flight

  #pragma unroll 1
  for (int t = 0; t < DIMS / KT; ++t) {
    const int b = PRE ? (t & 1) : 0;
    if (!PRE) { __syncthreads(); STAGE(0, t * KT); }
    __syncthreads();                          // tile-t data landed (all waves)
    const char* xd = smem + b * 65536;
    const char* yd = xd + 32768;
    bf16x8 af[4], bfr[4];

    // ---- P1: A mi0-3 kk0 + B kk0; issue next-tile stage; 16 MFMA ----
    #pragma unroll
    for (int mi = 0; mi < 4; ++mi) {
      int row = wr * 128 + mi * 16 + l16;
      af[mi] = *(const bf16x8*)(xd + row * 128 + ((g4 ^ (row & 7)) * 16));
    }
    #pragma unroll
    for (int ni = 0; ni < 4; ++ni) {
      int col = wc * 64 + ni * 16 + l16;
      bfr[ni] = *(const bf16x8*)(yd + col * 128 + ((g4 ^ (col & 7)) * 16));
    }
    if (PRE && t + 1 < DIMS / KT) STAGE(b ^ 1, (t + 1) * KT);
    __builtin_amdgcn_s_setprio(1);
    #pragma unroll
    for (int mi = 0; mi < 4; ++mi)
      #pragma unroll
      for (int ni = 0; ni < 4; ++ni)
        acc[mi][ni] = __builtin_amdgcn_mfma_f32_16x16x32_bf16(af[mi], bfr[ni], acc[mi][ni], 0, 0, 0);
    __builtin_amdgcn_s_setprio(0);
    __builtin_amdgcn_sched_barrier(0);

    // ---- P2: A mi4-7 kk0 (reuse B kk0); 16 MFMA ----
    #pragma unroll
    for (int mi = 0; mi < 4; ++mi) {
      int row = wr * 128 + (mi + 4) * 16 + l16;
      af[mi] = *(const bf16x8*)(xd + row * 128 + ((g4 ^ (row & 7)) * 16));
    }
    __builtin_amdgcn_s_setprio(1);
    #pragma unroll
    for (int mi = 0; mi < 4; ++mi)
      #pragma unroll
      for (int ni = 0; ni < 4; ++ni)
        acc[mi + 4][ni] = __builtin_amdgcn_mfma_f32_16x16x32_bf16(af[mi], bfr[ni], acc[mi + 4][ni], 0, 0, 0);
    __builtin_amdgcn_s_setprio(0);
    __builtin_amdgcn_sched_barrier(0);

    // ---- P3: A mi0-3 kk1 + B kk1; 16 MFMA ----
    #pragma unroll
    for (int mi = 0; mi < 4; ++mi) {
      int row = wr * 128 + mi * 16 + l16;
      af[mi] = *(const bf16x8*)(xd + row * 128 + (((4 + g4) ^ (row & 7)) * 16));
    }
    #pragma unroll
    for (int ni = 0; ni < 4; ++ni) {
      int col = wc * 64 + ni * 16 + l16;
      bfr[ni] = *(const bf16x8*)(yd + col * 128 + (((4 + g4) ^ (col & 7)) * 16));
    }
    __builtin_amdgcn_s_setprio(1);
    #pragma unroll
    for (int mi = 0; mi < 4; ++mi)
      #pragma unroll
      for (int ni = 0; ni < 4; ++ni)
        acc[mi][ni] = __builtin_amdgcn_mfma_f32_16x16x32_bf16(af[mi], bfr[ni], acc[mi][ni], 0, 0, 0);
    __builtin_amdgcn_s_setprio(0);
    __builtin_amdgcn_sched_barrier(0);

    // ---- P4: A mi4-7 kk1 (reuse B kk1); 16 MFMA ----
    #pragma unroll
    for (int mi = 0; mi < 4; ++mi) {
      int row = wr * 128 + (mi + 4) * 16 + l16;
      af[mi] = *(const bf16x8*)(xd + row * 128 + (((4 + g4) ^ (row & 7)) * 16));
    }
    __builtin_amdgcn_s_setprio(1);
    #pragma unroll
    for (int mi = 0; mi < 4; ++mi)
      #pragma unroll
      for (int ni = 0; ni < 4; ++ni)
        acc[mi + 4][ni] = __builtin_amdgcn_mfma_f32_16x16x32_bf16(af[mi], bfr[ni], acc[mi + 4][ni], 0, 0, 0);
    __builtin_amdgcn_s_setprio(0);
    __builtin_amdgcn_sched_barrier(0);
  }

  // ---- epilogue: 4 quarters of 64 rows through LDS ----
  #pragma unroll
  for (int q = 0; q < 4; ++q) {
    __syncthreads();                          // LDS free / prev quarter done
    if (wr == (q >> 1)) {
      #pragma unroll
      for (int mi2 = 0; mi2 < 4; ++mi2)
        #pragma unroll
        for (int j = 0; j < 4; ++j) {
          int rh = mi2 * 16 + g4 * 4 + j;
          int r = r0 + q * 64 + rh;
          float xv = x2[r];
          #pragma unroll
          for (int ni = 0; ni < 4; ++ni) {
            int cb = wc * 64 + ni * 16 + l16;
            float sq = fmaxf(xv + y2[c0 + cb] - 2.f * acc[(q & 1) * 4 + mi2][ni][j], 0.f);
            if (xs + r == ys + c0 + cb) sq = FINF;
            eps[rh * EPS_LD + cb] = sq;
          }
        }
    }
    __syncthreads();
    if (tid < 128) {                          // 2 threads per row, 128 cols each
      int rh = tid & 63, hf = tid >> 6;
      float t8[8];
      #pragma unroll
      for (int k = 0; k < 8; ++k) t8[k] = FINF;
      const float* rowp = eps + rh * EPS_LD + hf * 128;
      #pragma unroll
      for (int i = 0; i < 32; ++i) {
        int ii = (i + rh) & 31;               // rotate -> spread banks
        f32x4 v = *(const f32x4*)(rowp + ii * 4);
        if (v[0] < t8[7]) ins8(t8, v[0]);
        if (v[1] < t8[7]) ins8(t8, v[1]);
        if (v[2] < t8[7]) ins8(t8, v[2]);
        if (v[3] < t8[7]) ins8(t8, v[3]);
      }
      #pragma unroll
      for (int k = 0; k < 8; ++k) part[tid * 8 + k] = t8[k];
    }
    __syncthreads();
    if (tid < 64) {                           // merge the two halves
      float t8[8];
      #pragma unroll
      for (int k = 0; k < 8; ++k) t8[k] = FINF;
      #pragma unroll
      for (int v = 0; v < 8; ++v) {
        float d = part[tid * 8 + v];
        if (d < t8[7]) ins8(t8, d);
      }
      #pragma unroll
      for (int v = 0; v < 8; ++v) {
        float d = part[(tid + 64) * 8 + v];
        if (d < t8[7]) ins8(t8, d);
      }
      float* o = topk_out + (size_t)(r0 + q * 64 + tid) * (nchunks * 8) + blockIdx.y * 8;
      #pragma unroll
      for (int k = 0; k < 8; ++k) o[k] = t8[k];
    }
  }
}

// ---------------- phase B: merge chunk candidates + running min_dists ------
__global__ void knn_phaseB(const float* __restrict__ topk,
                           const float* __restrict__ mind_in,
                           float* __restrict__ out,
                           const int* __restrict__ xsp, int B, int nchunks) {
  int r = blockIdx.x * blockDim.x + threadIdx.x;
  if (r >= B) return;
  int x_start = *xsp;
  const float FINF = __builtin_inff();
  float lst[8];
  #pragma unroll
  for (int k = 0; k < 8; ++k) lst[k] = FINF;
  const int nc = nchunks * 8;
  const float* rowp = topk + (size_t)r * nc;
  for (int v = 0; v < nc; ++v) {
    float d = sqrtf(rowp[v]);
    if (d < lst[7]) ins8(lst, d);
  }
  const float* cur = mind_in + (size_t)(x_start + r) * KNN_K;
  #pragma unroll
  for (int k = 0; k < 8; ++k) {
    float d = cur[k];
    if (d < lst[7]) ins8(lst, d);
  }
  #pragma unroll
  for (int k = 0; k < 8; ++k) out[(size_t)(x_start + r) * KNN_K + k] = lst[k];
}

extern "C" void kernel_launch(void* const* d_in, const int* in_sizes, int n_in,
                              void* d_out, int out_size, void* d_ws, size_t ws_size,
                              hipStream_t stream) {
  const float* x = (const float*)d_in[0];
  const float* y = (const float*)d_in[1];
  const float* mind = (const float*)d_in[2];
  const int* xsp = (const int*)d_in[3];
  const int* ysp = (const int*)d_in[4];
  float* out = (float*)d_out;

  const int B = in_sizes[0] / DIMS;       // 2048
  const int M = in_sizes[1] / DIMS;       // 8192
  const int nch = M / BN;                 // 32

  float* y2 = (float*)d_ws;               // [M]
  float* x2 = y2 + M;                     // [B]
  float* topk = x2 + B;                   // [B][nch*8]
  size_t base = ((size_t)(M + B) + (size_t)B * nch * 8) * 4;
  base = (base + 255) & ~(size_t)255;
  bf16* xbw = (bf16*)((char*)d_ws + base);
  bf16* ybw = xbw + (size_t)B * DIMS;
  size_t need = base + ((size_t)B + (size_t)M) * DIMS * 2;
  bool pre = ws_size >= need;

  int nNorm = (B + M + 3) / 4;
  int n4 = out_size / 4;
  int nCopy = (n4 + 255) / 256;
  if (pre)
    prep_kernel<true><<<nNorm + nCopy, 256, 0, stream>>>(
        x, y, x2, y2, xbw, ybw, (const float4*)mind, (float4*)out, n4, B, M, nNorm);
  else
    prep_kernel<false><<<nNorm + nCopy, 256, 0, stream>>>(
        x, y, x2, y2, xbw, ybw, (const float4*)mind, (float4*)out, n4, B, M, nNorm);

  dim3 ga(B / BM, M / BN);
  if (pre)
    knn_mfma<true><<<ga, 512, 0, stream>>>(x, y, xbw, ybw, x2, y2, topk, xsp, ysp, B, M, nch);
  else
    knn_mfma<false><<<ga, 512, 0, stream>>>(x, y, xbw, ybw, x2, y2, topk, xsp, ysp, B, M, nch);

  knn_phaseB<<<(B + 255) / 256, 256, 0, stream>>>(topk, mind, out, xsp, B, nch);
}

// Round 5
// 140.922 us; speedup vs baseline: 5.2279x; 1.0968x over previous
//
#include <hip/hip_runtime.h>

#define DIMS 1024
#define KNN_K 8
#define BMT 64          // x rows per block (LDS-resident A tile)
#define BCOLS 512       // y cols per block (4 waves x 128)
#define KHALF 512       // K half resident in LDS (64 rows x 512 k x 2B = 64KB)

typedef __bf16 bf16;
typedef __bf16 bf16x8 __attribute__((ext_vector_type(8)));
typedef __bf16 bf16x4 __attribute__((ext_vector_type(4)));
typedef float f32x4 __attribute__((ext_vector_type(4)));

// branchless insert into ascending sorted-8 list (drops the largest)
__device__ __forceinline__ void ins8(float (&lst)[8], float d) {
  float c = d;
  #pragma unroll
  for (int i = 0; i < 8; ++i) {
    float lo = fminf(lst[i], c);
    c = fmaxf(lst[i], c);
    lst[i] = lo;
  }
}

__device__ __forceinline__ void gload_lds16(const void* g, void* l) {
  __builtin_amdgcn_global_load_lds(
      (const __attribute__((address_space(1))) void*)g,
      (__attribute__((address_space(3))) void*)l, 16, 0, 0);
}

// ---- prep: norms (+ optional bf16 convert) fused with min_dists->out copy --
template<bool PRE>
__global__ void prep_kernel(const float* __restrict__ x, const float* __restrict__ y,
                            float* __restrict__ x2, float* __restrict__ y2,
                            bf16* __restrict__ xb, bf16* __restrict__ yb,
                            const float4* __restrict__ mind4, float4* __restrict__ out4,
                            int n4, int B, int M, int nNormBlocks) {
  if ((int)blockIdx.x >= nNormBlocks) {        // tail blocks: full-buffer copy
    int i = ((int)blockIdx.x - nNormBlocks) * 256 + threadIdx.x;
    if (i < n4) out4[i] = mind4[i];
    return;
  }
  int wv = threadIdx.x >> 6;
  int lane = threadIdx.x & 63;
  int row = blockIdx.x * 4 + wv;
  const float* src;
  float* dst;
  bf16* bdst;
  if (row < M) {
    src = y + (size_t)row * DIMS; dst = y2 + row; bdst = yb + (size_t)row * DIMS;
  } else {
    int r = row - M;
    if (r >= B) return;
    src = x + (size_t)r * DIMS; dst = x2 + r; bdst = xb + (size_t)r * DIMS;
  }
  float s = 0.f;
  #pragma unroll
  for (int q = 0; q < DIMS / 4; q += 64) {
    float4 v = ((const float4*)src)[q + lane];
    s = fmaf(v.x, v.x, s); s = fmaf(v.y, v.y, s);
    s = fmaf(v.z, v.z, s); s = fmaf(v.w, v.w, s);
    if (PRE) {
      bf16x4 bv = {(bf16)v.x, (bf16)v.y, (bf16)v.z, (bf16)v.w};
      *(bf16x4*)(bdst + (size_t)(q + lane) * 4) = bv;
    }
  }
  #pragma unroll
  for (int off = 32; off; off >>= 1) s += __shfl_xor(s, off);
  if (lane == 0) *dst = s;
}

// ---------------- phase A: x-tile in LDS, y streamed; barrier-free K loop ---
// grid: 512 blocks (rowblk = bid>>4, colchunk = bid&15 -> colchunk%8 per XCD).
// block: 256 threads = 4 waves; wave wv owns cols c0+wv*128..+127, rows r0..+63.
template<bool PRE>
__global__ __launch_bounds__(256, 2) void knn_stream(
    const float* __restrict__ xf, const float* __restrict__ yf,
    const bf16* __restrict__ xb, const bf16* __restrict__ yb,
    const float* __restrict__ x2, const float* __restrict__ y2,
    float* __restrict__ topk_out,           // [B][nch*8] squared dists
    const int* __restrict__ xsp, const int* __restrict__ ysp,
    int B, int M, int nch) {
  __shared__ __align__(16) char smem[65536]; // A tile [64 rows][64 swz 16B slots]
  __shared__ float x2s[BMT];
  __shared__ float y2s[BCOLS];
  float* eps = (float*)smem;                 // epilogue reuse: col-major [128][66]
  float* part = (float*)(smem + 36864);      // [256][8]

  const int tid = threadIdx.x;
  const int wv = tid >> 6, l = tid & 63;
  const int g4 = l >> 4, l16 = l & 15;
  const int bid = blockIdx.x;
  const int colchunk = bid & 15, rowblk = bid >> 4;
  const int r0 = rowblk * BMT, c0 = colchunk * BCOLS;
  const int xs = *xsp, ys = *ysp;
  const float FINF = __builtin_inff();

  if (tid < BMT) x2s[tid] = x2[r0 + tid];
  y2s[tid] = y2[c0 + tid];
  y2s[256 + tid] = y2[c0 + 256 + tid];

  auto STAGE = [&](int kh) {                 // 64KB: rows p*4+wv, slot l (swz src)
    #pragma unroll
    for (int p = 0; p < 16; ++p) {
      int row = p * 4 + wv;
      int cs = l ^ (row & 7);                // inverse-swizzled global chunk
      if (PRE) {
        gload_lds16(xb + (size_t)(r0 + row) * DIMS + kh * KHALF + cs * 8,
                    smem + p * 4096 + tid * 16);
      } else {
        const float* g = xf + (size_t)(r0 + row) * DIMS + kh * KHALF + cs * 8;
        float4 a0 = *(const float4*)g;
        float4 a1 = *(const float4*)(g + 4);
        bf16x8 bx = {(bf16)a0.x, (bf16)a0.y, (bf16)a0.z, (bf16)a0.w,
                     (bf16)a1.x, (bf16)a1.y, (bf16)a1.z, (bf16)a1.w};
        *(bf16x8*)(smem + p * 4096 + tid * 16) = bx;
      }
    }
  };

  f32x4 acc[8][4];
  #pragma unroll
  for (int ct = 0; ct < 8; ++ct)
    #pragma unroll
    for (int mi = 0; mi < 4; ++mi)
      acc[ct][mi] = (f32x4){0.f, 0.f, 0.f, 0.f};

  STAGE(0);
  __syncthreads();                           // drains gload_lds, tile ready

  for (int kh = 0; kh < 2; ++kh) {
    if (kh) {
      __syncthreads();                       // all waves done reading half 0
      STAGE(1);
      __syncthreads();                       // half 1 landed
    }
    #pragma unroll 2
    for (int kt = 0; kt < 16; ++kt) {
      bf16x8 af[4];
      #pragma unroll
      for (int mi = 0; mi < 4; ++mi) {
        int row = mi * 16 + l16;
        int slot = (kt * 4 + g4) ^ (row & 7);
        af[mi] = *(const bf16x8*)(smem + row * 1024 + slot * 16);
      }
      bf16x8 bv[8];
      #pragma unroll
      for (int ct = 0; ct < 8; ++ct) {
        int col = c0 + wv * 128 + ct * 16 + l16;
        if (PRE) {
          bv[ct] = *(const bf16x8*)(yb + (size_t)col * DIMS + kh * KHALF + kt * 32 + g4 * 8);
        } else {
          const float* g = yf + (size_t)col * DIMS + kh * KHALF + kt * 32 + g4 * 8;
          float4 b0 = *(const float4*)g;
          float4 b1 = *(const float4*)(g + 4);
          bv[ct] = (bf16x8){(bf16)b0.x, (bf16)b0.y, (bf16)b0.z, (bf16)b0.w,
                            (bf16)b1.x, (bf16)b1.y, (bf16)b1.z, (bf16)b1.w};
        }
      }
      #pragma unroll
      for (int ct = 0; ct < 8; ++ct)
        #pragma unroll
        for (int mi = 0; mi < 4; ++mi)
          acc[ct][mi] = __builtin_amdgcn_mfma_f32_16x16x32_bf16(af[mi], bv[ct], acc[ct][mi], 0, 0, 0);
    }
  }

  // ---- epilogue: 4 wave phases through col-major eps [128 cols][66] ----
  float t8[8];
  #pragma unroll
  for (int k = 0; k < 8; ++k) t8[k] = FINF;

  #pragma unroll
  for (int w = 0; w < 4; ++w) {
    __syncthreads();                         // eps free (compute / prev scan done)
    if (wv == w) {
      #pragma unroll
      for (int ct = 0; ct < 8; ++ct)
        #pragma unroll
        for (int mi = 0; mi < 4; ++mi)
          #pragma unroll
          for (int j = 0; j < 4; ++j) {
            int rl = mi * 16 + g4 * 4 + j;   // x row within block
            int cl = ct * 16 + l16;          // y col within wave strip
            float sq = fmaxf(x2s[rl] + y2s[w * 128 + cl] - 2.f * acc[ct][mi][j], 0.f);
            if (xs + r0 + rl == ys + c0 + w * 128 + cl) sq = FINF;
            eps[cl * 66 + rl] = sq;
          }
    }
    __syncthreads();
    {
      int row = tid & 63, q = tid >> 6;      // 4 threads/row, 32 cols each
      #pragma unroll 4
      for (int i = 0; i < 32; ++i) {
        float d = eps[(q * 32 + i) * 66 + row];
        if (d < t8[7]) ins8(t8, d);
      }
    }
  }
  #pragma unroll
  for (int k = 0; k < 8; ++k) part[tid * 8 + k] = t8[k];
  __syncthreads();
  if (tid < 64) {                            // merge 4 quarter-scans per row
    float f8[8];
    #pragma unroll
    for (int k = 0; k < 8; ++k) f8[k] = FINF;
    #pragma unroll
    for (int q = 0; q < 4; ++q)
      #pragma unroll
      for (int v = 0; v < 8; ++v) {
        float d = part[(q * 64 + tid) * 8 + v];
        if (d < f8[7]) ins8(f8, d);
      }
    float* o = topk_out + (size_t)(r0 + tid) * (nch * 8) + colchunk * 8;
    #pragma unroll
    for (int k = 0; k < 8; ++k) o[k] = f8[k];
  }
}

// ---------------- phase B: merge chunk candidates + running min_dists ------
__global__ void knn_phaseB(const float* __restrict__ topk,
                           const float* __restrict__ mind_in,
                           float* __restrict__ out,
                           const int* __restrict__ xsp, int B, int nch) {
  int r = blockIdx.x * blockDim.x + threadIdx.x;
  if (r >= B) return;
  int x_start = *xsp;
  const float FINF = __builtin_inff();
  float lst[8];
  #pragma unroll
  for (int k = 0; k < 8; ++k) lst[k] = FINF;
  const int nc = nch * 8;
  const float* rowp = topk + (size_t)r * nc;
  for (int v = 0; v < nc; ++v) {
    float d = sqrtf(rowp[v]);
    if (d < lst[7]) ins8(lst, d);
  }
  const float* cur = mind_in + (size_t)(x_start + r) * KNN_K;
  #pragma unroll
  for (int k = 0; k < 8; ++k) {
    float d = cur[k];
    if (d < lst[7]) ins8(lst, d);
  }
  #pragma unroll
  for (int k = 0; k < 8; ++k) out[(size_t)(x_start + r) * KNN_K + k] = lst[k];
}

extern "C" void kernel_launch(void* const* d_in, const int* in_sizes, int n_in,
                              void* d_out, int out_size, void* d_ws, size_t ws_size,
                              hipStream_t stream) {
  const float* x = (const float*)d_in[0];
  const float* y = (const float*)d_in[1];
  const float* mind = (const float*)d_in[2];
  const int* xsp = (const int*)d_in[3];
  const int* ysp = (const int*)d_in[4];
  float* out = (float*)d_out;

  const int B = in_sizes[0] / DIMS;       // 2048
  const int M = in_sizes[1] / DIMS;       // 8192
  const int nch = M / BCOLS;              // 16

  float* y2 = (float*)d_ws;               // [M]
  float* x2 = y2 + M;                     // [B]
  float* topk = x2 + B;                   // [B][nch*8]
  size_t base = ((size_t)(M + B) + (size_t)B * nch * 8) * 4;
  base = (base + 255) & ~(size_t)255;
  bf16* xbw = (bf16*)((char*)d_ws + base);
  bf16* ybw = xbw + (size_t)B * DIMS;
  size_t need = base + ((size_t)B + (size_t)M) * DIMS * 2;
  bool pre = ws_size >= need;

  int nNorm = (B + M + 3) / 4;
  int n4 = out_size / 4;
  int nCopy = (n4 + 255) / 256;
  if (pre)
    prep_kernel<true><<<nNorm + nCopy, 256, 0, stream>>>(
        x, y, x2, y2, xbw, ybw, (const float4*)mind, (float4*)out, n4, B, M, nNorm);
  else
    prep_kernel<false><<<nNorm + nCopy, 256, 0, stream>>>(
        x, y, x2, y2, xbw, ybw, (const float4*)mind, (float4*)out, n4, B, M, nNorm);

  int nBlocks = (B / BMT) * nch;          // 32 x 16 = 512
  if (pre)
    knn_stream<true><<<nBlocks, 256, 0, stream>>>(x, y, xbw, ybw, x2, y2, topk, xsp, ysp, B, M, nch);
  else
    knn_stream<false><<<nBlocks, 256, 0, stream>>>(x, y, xbw, ybw, x2, y2, topk, xsp, ysp, B, M, nch);

  knn_phaseB<<<(B + 255) / 256, 256, 0, stream>>>(topk, mind, out, xsp, B, nch);
}